// Round 1
// baseline (759.511 us; speedup 1.0000x reference)
//
#include <hip/hip_runtime.h>

#define DD 128

// ---------------- CSR build ----------------
__global__ void k_hist(const int* __restrict__ dst, int* __restrict__ counts, int E) {
    int e = blockIdx.x * blockDim.x + threadIdx.x;
    if (e < E) atomicAdd(&counts[dst[e]], 1);
}

__global__ __launch_bounds__(1024) void k_scan_block_sums(const int* __restrict__ counts,
                                                          int* __restrict__ blockSums, int N) {
    __shared__ int s[1024];
    int t = threadIdx.x;
    int idx = blockIdx.x * 1024 + t;
    s[t] = (idx < N) ? counts[idx] : 0;
    __syncthreads();
    for (int off = 512; off > 0; off >>= 1) {
        if (t < off) s[t] += s[t + off];
        __syncthreads();
    }
    if (t == 0) blockSums[blockIdx.x] = s[0];
}

__global__ __launch_bounds__(1024) void k_scan_offsets(const int* __restrict__ blockSums,
                                                       int* __restrict__ blockOffs, int nb,
                                                       int* __restrict__ row_end) {
    __shared__ int s[1024];
    int t = threadIdx.x;
    int v = (t < nb) ? blockSums[t] : 0;
    s[t] = v;
    __syncthreads();
    for (int off = 1; off < 1024; off <<= 1) {
        int x = (t >= off) ? s[t - off] : 0;
        __syncthreads();
        s[t] += x;
        __syncthreads();
    }
    if (t < nb) blockOffs[t] = s[t] - v;
    if (t == 1023) *row_end = s[t];   // total edge count
}

__global__ __launch_bounds__(1024) void k_scan_final(const int* __restrict__ counts,
                                                     const int* __restrict__ blockOffs,
                                                     int* __restrict__ row_start,
                                                     int* __restrict__ cursor, int N) {
    __shared__ int s[1024];
    int t = threadIdx.x;
    int idx = blockIdx.x * 1024 + t;
    int v = (idx < N) ? counts[idx] : 0;
    s[t] = v;
    __syncthreads();
    for (int off = 1; off < 1024; off <<= 1) {
        int x = (t >= off) ? s[t - off] : 0;
        __syncthreads();
        s[t] += x;
        __syncthreads();
    }
    int excl = s[t] - v + blockOffs[blockIdx.x];
    if (idx < N) { row_start[idx] = excl; cursor[idx] = excl; }
}

__global__ void k_place(const int* __restrict__ src, const int* __restrict__ dst,
                        const float* __restrict__ w, int* __restrict__ cursor,
                        int* __restrict__ s_src, float* __restrict__ s_w, int E) {
    int e = blockIdx.x * blockDim.x + threadIdx.x;
    if (e >= E) return;
    int d = dst[e];
    int pos = atomicAdd(&cursor[d], 1);
    s_src[pos] = src[e];
    s_w[pos] = w[e];
}

// ---------------- aggregation: one wave per dst node ----------------
__global__ __launch_bounds__(256) void k_aggregate(const float* __restrict__ x,
                                                   const int* __restrict__ row_start,
                                                   const int* __restrict__ s_src,
                                                   const float* __restrict__ s_w,
                                                   float* __restrict__ out, int N) {
    int wid = (blockIdx.x * blockDim.x + threadIdx.x) >> 6;
    int lane = threadIdx.x & 63;
    if (wid >= N) return;
    int beg = row_start[wid];
    int end = row_start[wid + 1];
    float a0 = 0.f, a1 = 0.f;
    for (int i = beg; i < end; ++i) {
        int s = s_src[i];
        float w = s_w[i];
        const float* xp = x + (size_t)s * DD;
        a0 = fmaf(xp[lane], w, a0);
        a1 = fmaf(xp[lane + 64], w, a1);
    }
    out[(size_t)wid * DD + lane] = a0;
    out[(size_t)wid * DD + lane + 64] = a1;
}

// ---------------- GEMM: C = relu(A @ W + b) [+ resid], 128-row tiles ----------------
__global__ __launch_bounds__(256) void k_gemm_relu(const float* __restrict__ A,
                                                   const float* __restrict__ W,
                                                   const float* __restrict__ bias,
                                                   const float* __restrict__ resid,
                                                   float* __restrict__ C, int nrows) {
    __shared__ float At[16][DD];  // transposed A chunk: At[k][r]
    __shared__ float Ws[16][DD];  // Ws[k][c]
    int tid = threadIdx.x;
    int tr = tid >> 4;   // 0..15 -> rows tr*8..tr*8+7
    int tc = tid & 15;   // 0..15 -> cols tc*8..tc*8+7
    int row0 = blockIdx.x * DD;

    float acc[8][8] = {};

    for (int k0 = 0; k0 < DD; k0 += 16) {
        // stage A chunk (transposed): 128 rows x 16 k = 512 float4 loads
        #pragma unroll
        for (int l = 0; l < 2; ++l) {
            int f = tid + l * 256;
            int r = f >> 2;
            int kk = (f & 3) * 4;
            int row = row0 + r;
            float4 v = make_float4(0.f, 0.f, 0.f, 0.f);
            if (row < nrows)
                v = *reinterpret_cast<const float4*>(&A[(size_t)row * DD + k0 + kk]);
            At[kk + 0][r] = v.x; At[kk + 1][r] = v.y;
            At[kk + 2][r] = v.z; At[kk + 3][r] = v.w;
        }
        // stage W chunk: contiguous 2048 floats
        #pragma unroll
        for (int l = 0; l < 2; ++l) {
            int f = tid + l * 256;
            *reinterpret_cast<float4*>(&((float*)Ws)[f * 4]) =
                *reinterpret_cast<const float4*>(&W[k0 * DD + f * 4]);
        }
        __syncthreads();
        #pragma unroll
        for (int kk = 0; kk < 16; ++kk) {
            float4 a0 = *reinterpret_cast<const float4*>(&At[kk][tr * 8]);
            float4 a1 = *reinterpret_cast<const float4*>(&At[kk][tr * 8 + 4]);
            float4 w0 = *reinterpret_cast<const float4*>(&Ws[kk][tc * 8]);
            float4 w1 = *reinterpret_cast<const float4*>(&Ws[kk][tc * 8 + 4]);
            float av[8] = {a0.x, a0.y, a0.z, a0.w, a1.x, a1.y, a1.z, a1.w};
            float wv[8] = {w0.x, w0.y, w0.z, w0.w, w1.x, w1.y, w1.z, w1.w};
            #pragma unroll
            for (int i = 0; i < 8; ++i)
                #pragma unroll
                for (int j = 0; j < 8; ++j)
                    acc[i][j] = fmaf(av[i], wv[j], acc[i][j]);
        }
        __syncthreads();
    }

    float bv[8];
    #pragma unroll
    for (int j = 0; j < 8; ++j) bv[j] = bias[tc * 8 + j];

    #pragma unroll
    for (int i = 0; i < 8; ++i) {
        int row = row0 + tr * 8 + i;
        if (row >= nrows) break;
        size_t base = (size_t)row * DD + tc * 8;
        float o[8];
        #pragma unroll
        for (int j = 0; j < 8; ++j) {
            float v = acc[i][j] + bv[j];
            o[j] = v > 0.f ? v : 0.f;
        }
        if (resid) {
            #pragma unroll
            for (int j = 0; j < 8; ++j) o[j] += resid[base + j];
        }
        *reinterpret_cast<float4*>(&C[base]) = make_float4(o[0], o[1], o[2], o[3]);
        *reinterpret_cast<float4*>(&C[base + 4]) = make_float4(o[4], o[5], o[6], o[7]);
    }
}

// ---------------- per-subgraph mean pool + target residual ----------------
__global__ __launch_bounds__(128) void k_pool(const float* __restrict__ h,
                                              const int* __restrict__ target,
                                              const float* __restrict__ size_subg,
                                              float* __restrict__ pooled, int SZ) {
    int b = blockIdx.x;
    int d = threadIdx.x;
    const float* hp = h + (size_t)b * SZ * DD;
    float s = 0.f;
    for (int n = 0; n < SZ; ++n) s += hp[(size_t)n * DD + d];
    int t = target[b];
    float p = s / size_subg[b] + h[(size_t)t * DD + d];
    pooled[b * DD + d] = p;
}

// ---------------- final: relu(pooled @ Wp + bp), L2-normalize rows ----------------
__global__ __launch_bounds__(128) void k_final(const float* __restrict__ pooled,
                                               const float* __restrict__ Wp,
                                               const float* __restrict__ bp,
                                               float* __restrict__ out) {
    __shared__ float p[DD];
    __shared__ float wsum[2];
    int b = blockIdx.x;
    int c = threadIdx.x;
    p[c] = pooled[b * DD + c];
    __syncthreads();
    float acc = 0.f;
    #pragma unroll 4
    for (int k = 0; k < DD; ++k) acc = fmaf(p[k], Wp[k * DD + c], acc);
    float e = acc + bp[c];
    e = e > 0.f ? e : 0.f;
    float sq = e * e;
    #pragma unroll
    for (int off = 32; off > 0; off >>= 1) sq += __shfl_down(sq, off, 64);
    int lane = c & 63, w = c >> 6;
    if (lane == 0) wsum[w] = sq;
    __syncthreads();
    float norm = sqrtf(wsum[0] + wsum[1]);
    float scale = 1.f / fmaxf(norm, 1e-12f);
    out[b * DD + c] = e * scale;
}

extern "C" void kernel_launch(void* const* d_in, const int* in_sizes, int n_in,
                              void* d_out, int out_size, void* d_ws, size_t ws_size,
                              hipStream_t stream) {
    const float* feat      = (const float*)d_in[0];
    const float* edge_w    = (const float*)d_in[1];
    const float* W1        = (const float*)d_in[2];
    const float* b1        = (const float*)d_in[3];
    const float* W2        = (const float*)d_in[4];
    const float* b2        = (const float*)d_in[5];
    const float* Wp        = (const float*)d_in[6];
    const float* bp        = (const float*)d_in[7];
    const float* size_subg = (const float*)d_in[8];
    const int*   edge_src  = (const int*)d_in[9];
    const int*   edge_dst  = (const int*)d_in[10];
    const int*   target    = (const int*)d_in[12];

    const int N  = in_sizes[0] / DD;
    const int E  = in_sizes[1];
    const int B  = in_sizes[8];
    const int SZ = N / B;

    char* ws = (char*)d_ws;
    size_t off = 0;
    auto alloc = [&](size_t bytes) {
        void* p = ws + off;
        off += (bytes + 255) & ~(size_t)255;
        return p;
    };
    float* X         = (float*)alloc((size_t)N * DD * 4);   // agg1 -> agg2 -> h (in place)
    float* Y         = (float*)alloc((size_t)N * DD * 4);   // h1
    int*   counts    = (int*)alloc((size_t)N * 4);
    int*   row_start = (int*)alloc(((size_t)N + 1) * 4);
    int*   cursor    = (int*)alloc((size_t)N * 4);
    int nb = (N + 1023) / 1024;
    int*   blockSums = (int*)alloc((size_t)nb * 4);
    int*   blockOffs = (int*)alloc((size_t)nb * 4);
    int*   s_src     = (int*)alloc((size_t)E * 4);
    float* s_w       = (float*)alloc((size_t)E * 4);
    float* pooled    = (float*)alloc((size_t)B * DD * 4);

    // ---- CSR by dst (rebuilt every call; ws is re-poisoned) ----
    hipMemsetAsync(counts, 0, (size_t)N * 4, stream);
    k_hist<<<(E + 255) / 256, 256, 0, stream>>>(edge_dst, counts, E);
    k_scan_block_sums<<<nb, 1024, 0, stream>>>(counts, blockSums, N);
    k_scan_offsets<<<1, 1024, 0, stream>>>(blockSums, blockOffs, nb, row_start + N);
    k_scan_final<<<nb, 1024, 0, stream>>>(counts, blockOffs, row_start, cursor, N);
    k_place<<<(E + 255) / 256, 256, 0, stream>>>(edge_src, edge_dst, edge_w, cursor,
                                                 s_src, s_w, E);

    int aggBlocks  = (N * 64 + 255) / 256;   // one wave per node
    int gemmBlocks = (N + DD - 1) / DD;

    // layer 1: agg1 = A_hat @ feat ; h1 = relu(agg1 @ W1 + b1)
    k_aggregate<<<aggBlocks, 256, 0, stream>>>(feat, row_start, s_src, s_w, X, N);
    k_gemm_relu<<<gemmBlocks, 256, 0, stream>>>(X, W1, b1, nullptr, Y, N);
    // layer 2: agg2 = A_hat @ h1 ; h = h1 + relu(agg2 @ W2 + b2)  (in place into X)
    k_aggregate<<<aggBlocks, 256, 0, stream>>>(Y, row_start, s_src, s_w, X, N);
    k_gemm_relu<<<gemmBlocks, 256, 0, stream>>>(X, W2, b2, Y, X, N);
    // pool + final
    k_pool<<<B, 128, 0, stream>>>(X, target, size_subg, pooled, SZ);
    k_final<<<B, 128, 0, stream>>>(pooled, Wp, bp, (float*)d_out);
}

// Round 2
// 676.450 us; speedup vs baseline: 1.1228x; 1.1228x over previous
//
#include <hip/hip_runtime.h>

#define DD 128

// ---------------- CSR build ----------------
__global__ void k_hist(const int* __restrict__ dst, int* __restrict__ counts, int E) {
    int e = blockIdx.x * blockDim.x + threadIdx.x;
    if (e < E) atomicAdd(&counts[dst[e]], 1);
}

__global__ __launch_bounds__(1024) void k_scan_block_sums(const int* __restrict__ counts,
                                                          int* __restrict__ blockSums, int N) {
    __shared__ int s[1024];
    int t = threadIdx.x;
    int idx = blockIdx.x * 1024 + t;
    s[t] = (idx < N) ? counts[idx] : 0;
    __syncthreads();
    for (int off = 512; off > 0; off >>= 1) {
        if (t < off) s[t] += s[t + off];
        __syncthreads();
    }
    if (t == 0) blockSums[blockIdx.x] = s[0];
}

__global__ __launch_bounds__(1024) void k_scan_offsets(const int* __restrict__ blockSums,
                                                       int* __restrict__ blockOffs, int nb,
                                                       int* __restrict__ row_end) {
    __shared__ int s[1024];
    int t = threadIdx.x;
    int v = (t < nb) ? blockSums[t] : 0;
    s[t] = v;
    __syncthreads();
    for (int off = 1; off < 1024; off <<= 1) {
        int x = (t >= off) ? s[t - off] : 0;
        __syncthreads();
        s[t] += x;
        __syncthreads();
    }
    if (t < nb) blockOffs[t] = s[t] - v;
    if (t == 1023) *row_end = s[t];   // total edge count
}

__global__ __launch_bounds__(1024) void k_scan_final(const int* __restrict__ counts,
                                                     const int* __restrict__ blockOffs,
                                                     int* __restrict__ row_start,
                                                     int* __restrict__ cursor, int N) {
    __shared__ int s[1024];
    int t = threadIdx.x;
    int idx = blockIdx.x * 1024 + t;
    int v = (idx < N) ? counts[idx] : 0;
    s[t] = v;
    __syncthreads();
    for (int off = 1; off < 1024; off <<= 1) {
        int x = (t >= off) ? s[t - off] : 0;
        __syncthreads();
        s[t] += x;
        __syncthreads();
    }
    int excl = s[t] - v + blockOffs[blockIdx.x];
    if (idx < N) { row_start[idx] = excl; cursor[idx] = excl; }
}

__global__ void k_place(const int* __restrict__ src, const int* __restrict__ dst,
                        const float* __restrict__ w, int* __restrict__ cursor,
                        int2* __restrict__ edges, int E) {
    int e = blockIdx.x * blockDim.x + threadIdx.x;
    if (e >= E) return;
    int d = dst[e];
    int pos = atomicAdd(&cursor[d], 1);
    edges[pos] = make_int2(src[e], __float_as_int(w[e]));   // one 8B scattered store
}

// ---------------- aggregation: one wave per dst node, float2 lanes, unroll 4 ----
__global__ __launch_bounds__(256) void k_aggregate(const float* __restrict__ x,
                                                   const int* __restrict__ row_start,
                                                   const int2* __restrict__ edges,
                                                   float* __restrict__ out, int N) {
    int wid = (blockIdx.x * blockDim.x + threadIdx.x) >> 6;
    int lane = threadIdx.x & 63;
    if (wid >= N) return;
    int beg = row_start[wid];
    int end = row_start[wid + 1];
    float a0 = 0.f, a1 = 0.f;
    int i = beg;
    // unrolled by 4: load 4 edge records first, then 4 independent dwordx2 gathers
    for (; i + 4 <= end; i += 4) {
        int2 e0 = edges[i + 0];
        int2 e1 = edges[i + 1];
        int2 e2 = edges[i + 2];
        int2 e3 = edges[i + 3];
        float2 v0 = *reinterpret_cast<const float2*>(&x[(size_t)e0.x * DD + lane * 2]);
        float2 v1 = *reinterpret_cast<const float2*>(&x[(size_t)e1.x * DD + lane * 2]);
        float2 v2 = *reinterpret_cast<const float2*>(&x[(size_t)e2.x * DD + lane * 2]);
        float2 v3 = *reinterpret_cast<const float2*>(&x[(size_t)e3.x * DD + lane * 2]);
        float w0 = __int_as_float(e0.y), w1 = __int_as_float(e1.y);
        float w2 = __int_as_float(e2.y), w3 = __int_as_float(e3.y);
        a0 = fmaf(v0.x, w0, a0); a1 = fmaf(v0.y, w0, a1);
        a0 = fmaf(v1.x, w1, a0); a1 = fmaf(v1.y, w1, a1);
        a0 = fmaf(v2.x, w2, a0); a1 = fmaf(v2.y, w2, a1);
        a0 = fmaf(v3.x, w3, a0); a1 = fmaf(v3.y, w3, a1);
    }
    for (; i < end; ++i) {
        int2 e0 = edges[i];
        float2 v0 = *reinterpret_cast<const float2*>(&x[(size_t)e0.x * DD + lane * 2]);
        float w0 = __int_as_float(e0.y);
        a0 = fmaf(v0.x, w0, a0); a1 = fmaf(v0.y, w0, a1);
    }
    *reinterpret_cast<float2*>(&out[(size_t)wid * DD + lane * 2]) = make_float2(a0, a1);
}

// ---------------- GEMM: C = relu(A @ W + b) [+ resid], 128-row tiles ----------------
__global__ __launch_bounds__(256) void k_gemm_relu(const float* __restrict__ A,
                                                   const float* __restrict__ W,
                                                   const float* __restrict__ bias,
                                                   const float* __restrict__ resid,
                                                   float* __restrict__ C, int nrows) {
    __shared__ float At[16][DD];  // transposed A chunk: At[k][r]
    __shared__ float Ws[16][DD];  // Ws[k][c]
    int tid = threadIdx.x;
    int tr = tid >> 4;   // 0..15 -> rows tr*8..tr*8+7
    int tc = tid & 15;   // 0..15 -> cols tc*8..tc*8+7
    int row0 = blockIdx.x * DD;

    float acc[8][8] = {};

    for (int k0 = 0; k0 < DD; k0 += 16) {
        #pragma unroll
        for (int l = 0; l < 2; ++l) {
            int f = tid + l * 256;
            int r = f >> 2;
            int kk = (f & 3) * 4;
            int row = row0 + r;
            float4 v = make_float4(0.f, 0.f, 0.f, 0.f);
            if (row < nrows)
                v = *reinterpret_cast<const float4*>(&A[(size_t)row * DD + k0 + kk]);
            At[kk + 0][r] = v.x; At[kk + 1][r] = v.y;
            At[kk + 2][r] = v.z; At[kk + 3][r] = v.w;
        }
        #pragma unroll
        for (int l = 0; l < 2; ++l) {
            int f = tid + l * 256;
            *reinterpret_cast<float4*>(&((float*)Ws)[f * 4]) =
                *reinterpret_cast<const float4*>(&W[k0 * DD + f * 4]);
        }
        __syncthreads();
        #pragma unroll
        for (int kk = 0; kk < 16; ++kk) {
            float4 a0 = *reinterpret_cast<const float4*>(&At[kk][tr * 8]);
            float4 a1 = *reinterpret_cast<const float4*>(&At[kk][tr * 8 + 4]);
            float4 w0 = *reinterpret_cast<const float4*>(&Ws[kk][tc * 8]);
            float4 w1 = *reinterpret_cast<const float4*>(&Ws[kk][tc * 8 + 4]);
            float av[8] = {a0.x, a0.y, a0.z, a0.w, a1.x, a1.y, a1.z, a1.w};
            float wv[8] = {w0.x, w0.y, w0.z, w0.w, w1.x, w1.y, w1.z, w1.w};
            #pragma unroll
            for (int i = 0; i < 8; ++i)
                #pragma unroll
                for (int j = 0; j < 8; ++j)
                    acc[i][j] = fmaf(av[i], wv[j], acc[i][j]);
        }
        __syncthreads();
    }

    float bv[8];
    #pragma unroll
    for (int j = 0; j < 8; ++j) bv[j] = bias[tc * 8 + j];

    #pragma unroll
    for (int i = 0; i < 8; ++i) {
        int row = row0 + tr * 8 + i;
        if (row >= nrows) break;
        size_t base = (size_t)row * DD + tc * 8;
        float o[8];
        #pragma unroll
        for (int j = 0; j < 8; ++j) {
            float v = acc[i][j] + bv[j];
            o[j] = v > 0.f ? v : 0.f;
        }
        if (resid) {
            #pragma unroll
            for (int j = 0; j < 8; ++j) o[j] += resid[base + j];
        }
        *reinterpret_cast<float4*>(&C[base]) = make_float4(o[0], o[1], o[2], o[3]);
        *reinterpret_cast<float4*>(&C[base + 4]) = make_float4(o[4], o[5], o[6], o[7]);
    }
}

// ---------------- per-subgraph mean pool + target residual ----------------
__global__ __launch_bounds__(128) void k_pool(const float* __restrict__ h,
                                              const int* __restrict__ target,
                                              const float* __restrict__ size_subg,
                                              float* __restrict__ pooled, int SZ) {
    int b = blockIdx.x;
    int d = threadIdx.x;
    const float* hp = h + (size_t)b * SZ * DD;
    float s = 0.f;
    for (int n = 0; n < SZ; ++n) s += hp[(size_t)n * DD + d];
    int t = target[b];
    float p = s / size_subg[b] + h[(size_t)t * DD + d];
    pooled[b * DD + d] = p;
}

// ---------------- final: relu(pooled @ Wp + bp), L2-normalize rows ----------------
__global__ __launch_bounds__(128) void k_final(const float* __restrict__ pooled,
                                               const float* __restrict__ Wp,
                                               const float* __restrict__ bp,
                                               float* __restrict__ out) {
    __shared__ float p[DD];
    __shared__ float wsum[2];
    int b = blockIdx.x;
    int c = threadIdx.x;
    p[c] = pooled[b * DD + c];
    __syncthreads();
    float acc = 0.f;
    #pragma unroll 4
    for (int k = 0; k < DD; ++k) acc = fmaf(p[k], Wp[k * DD + c], acc);
    float e = acc + bp[c];
    e = e > 0.f ? e : 0.f;
    float sq = e * e;
    #pragma unroll
    for (int off = 32; off > 0; off >>= 1) sq += __shfl_down(sq, off, 64);
    int lane = c & 63, w = c >> 6;
    if (lane == 0) wsum[w] = sq;
    __syncthreads();
    float norm = sqrtf(wsum[0] + wsum[1]);
    float scale = 1.f / fmaxf(norm, 1e-12f);
    out[b * DD + c] = e * scale;
}

extern "C" void kernel_launch(void* const* d_in, const int* in_sizes, int n_in,
                              void* d_out, int out_size, void* d_ws, size_t ws_size,
                              hipStream_t stream) {
    const float* feat      = (const float*)d_in[0];
    const float* edge_w    = (const float*)d_in[1];
    const float* W1        = (const float*)d_in[2];
    const float* b1        = (const float*)d_in[3];
    const float* W2        = (const float*)d_in[4];
    const float* b2        = (const float*)d_in[5];
    const float* Wp        = (const float*)d_in[6];
    const float* bp        = (const float*)d_in[7];
    const float* size_subg = (const float*)d_in[8];
    const int*   edge_src  = (const int*)d_in[9];
    const int*   edge_dst  = (const int*)d_in[10];
    const int*   target    = (const int*)d_in[12];

    const int N  = in_sizes[0] / DD;
    const int E  = in_sizes[1];
    const int B  = in_sizes[8];
    const int SZ = N / B;

    char* ws = (char*)d_ws;
    size_t off = 0;
    auto alloc = [&](size_t bytes) {
        void* p = ws + off;
        off += (bytes + 255) & ~(size_t)255;
        return p;
    };
    float* X         = (float*)alloc((size_t)N * DD * 4);   // agg1 -> agg2 -> h (in place)
    float* Y         = (float*)alloc((size_t)N * DD * 4);   // h1
    int*   counts    = (int*)alloc((size_t)N * 4);
    int*   row_start = (int*)alloc(((size_t)N + 1) * 4);
    int*   cursor    = (int*)alloc((size_t)N * 4);
    int nb = (N + 1023) / 1024;
    int*   blockSums = (int*)alloc((size_t)nb * 4);
    int*   blockOffs = (int*)alloc((size_t)nb * 4);
    int2*  edges     = (int2*)alloc((size_t)E * 8);
    float* pooled    = (float*)alloc((size_t)B * DD * 4);

    // ---- CSR by dst (rebuilt every call; ws is re-poisoned) ----
    hipMemsetAsync(counts, 0, (size_t)N * 4, stream);
    k_hist<<<(E + 255) / 256, 256, 0, stream>>>(edge_dst, counts, E);
    k_scan_block_sums<<<nb, 1024, 0, stream>>>(counts, blockSums, N);
    k_scan_offsets<<<1, 1024, 0, stream>>>(blockSums, blockOffs, nb, row_start + N);
    k_scan_final<<<nb, 1024, 0, stream>>>(counts, blockOffs, row_start, cursor, N);
    k_place<<<(E + 255) / 256, 256, 0, stream>>>(edge_src, edge_dst, edge_w, cursor,
                                                 edges, E);

    int aggBlocks  = (N * 64 + 255) / 256;   // one wave per node
    int gemmBlocks = (N + DD - 1) / DD;

    // layer 1: agg1 = A_hat @ feat ; h1 = relu(agg1 @ W1 + b1)
    k_aggregate<<<aggBlocks, 256, 0, stream>>>(feat, row_start, edges, X, N);
    k_gemm_relu<<<gemmBlocks, 256, 0, stream>>>(X, W1, b1, nullptr, Y, N);
    // layer 2: agg2 = A_hat @ h1 ; h = h1 + relu(agg2 @ W2 + b2)  (in place into X)
    k_aggregate<<<aggBlocks, 256, 0, stream>>>(Y, row_start, edges, X, N);
    k_gemm_relu<<<gemmBlocks, 256, 0, stream>>>(X, W2, b2, Y, X, N);
    // pool + final
    k_pool<<<B, 128, 0, stream>>>(X, target, size_subg, pooled, SZ);
    k_final<<<B, 128, 0, stream>>>(pooled, Wp, bp, (float*)d_out);
}

// Round 3
// 610.153 us; speedup vs baseline: 1.2448x; 1.1087x over previous
//
#include <hip/hip_runtime.h>

#define DD 128

typedef _Float16 half8 __attribute__((ext_vector_type(8)));
typedef _Float16 half2v __attribute__((ext_vector_type(2)));
typedef _Float16 half4v __attribute__((ext_vector_type(4)));
typedef float floatx4 __attribute__((ext_vector_type(4)));

// ---------------- CSR build ----------------
__global__ void k_hist(const int* __restrict__ dst, int* __restrict__ counts, int E) {
    int e = blockIdx.x * blockDim.x + threadIdx.x;
    if (e < E) atomicAdd(&counts[dst[e]], 1);
}

__global__ __launch_bounds__(1024) void k_scan_block_sums(const int* __restrict__ counts,
                                                          int* __restrict__ blockSums, int N) {
    __shared__ int s[1024];
    int t = threadIdx.x;
    int idx = blockIdx.x * 1024 + t;
    s[t] = (idx < N) ? counts[idx] : 0;
    __syncthreads();
    for (int off = 512; off > 0; off >>= 1) {
        if (t < off) s[t] += s[t + off];
        __syncthreads();
    }
    if (t == 0) blockSums[blockIdx.x] = s[0];
}

__global__ __launch_bounds__(1024) void k_scan_offsets(const int* __restrict__ blockSums,
                                                       int* __restrict__ blockOffs, int nb,
                                                       int* __restrict__ row_end) {
    __shared__ int s[1024];
    int t = threadIdx.x;
    int v = (t < nb) ? blockSums[t] : 0;
    s[t] = v;
    __syncthreads();
    for (int off = 1; off < 1024; off <<= 1) {
        int x = (t >= off) ? s[t - off] : 0;
        __syncthreads();
        s[t] += x;
        __syncthreads();
    }
    if (t < nb) blockOffs[t] = s[t] - v;
    if (t == 1023) *row_end = s[t];   // total edge count
}

__global__ __launch_bounds__(1024) void k_scan_final(const int* __restrict__ counts,
                                                     const int* __restrict__ blockOffs,
                                                     int* __restrict__ row_start,
                                                     int* __restrict__ cursor, int N) {
    __shared__ int s[1024];
    int t = threadIdx.x;
    int idx = blockIdx.x * 1024 + t;
    int v = (idx < N) ? counts[idx] : 0;
    s[t] = v;
    __syncthreads();
    for (int off = 1; off < 1024; off <<= 1) {
        int x = (t >= off) ? s[t - off] : 0;
        __syncthreads();
        s[t] += x;
        __syncthreads();
    }
    int excl = s[t] - v + blockOffs[blockIdx.x];
    if (idx < N) { row_start[idx] = excl; cursor[idx] = excl; }
}

__global__ void k_place(const int* __restrict__ src, const int* __restrict__ dst,
                        const float* __restrict__ w, int* __restrict__ cursor,
                        int2* __restrict__ edges, int E) {
    int e = blockIdx.x * blockDim.x + threadIdx.x;
    if (e >= E) return;
    int d = dst[e];
    int pos = atomicAdd(&cursor[d], 1);
    edges[pos] = make_int2(src[e], __float_as_int(w[e]));
}

// ---------------- casts ----------------
__global__ void k_cast_f2h(const float* __restrict__ in, _Float16* __restrict__ out, int n4) {
    int i = blockIdx.x * blockDim.x + threadIdx.x;
    if (i >= n4) return;
    float4 v = reinterpret_cast<const float4*>(in)[i];
    half4v h;
    h.x = (_Float16)v.x; h.y = (_Float16)v.y; h.z = (_Float16)v.z; h.w = (_Float16)v.w;
    reinterpret_cast<half4v*>(out)[i] = h;
}

// Wt[n][k] = (half)W[k][n], both 128x128
__global__ void k_cast_wT(const float* __restrict__ W, _Float16* __restrict__ Wt) {
    int idx = blockIdx.x * blockDim.x + threadIdx.x;   // 0..16383
    int n = idx >> 7, k = idx & 127;
    Wt[n * DD + k] = (_Float16)W[k * DD + n];
}

// ---------------- aggregation: one wave per dst node, fp16 gather, unroll 8 ----
__global__ __launch_bounds__(256) void k_aggregate_h(const _Float16* __restrict__ x,
                                                     const int* __restrict__ row_start,
                                                     const int2* __restrict__ edges,
                                                     _Float16* __restrict__ out, int N) {
    int wid = (blockIdx.x * blockDim.x + threadIdx.x) >> 6;
    int lane = threadIdx.x & 63;
    if (wid >= N) return;
    int beg = row_start[wid];
    int end = row_start[wid + 1];
    float a0 = 0.f, a1 = 0.f;
    int i = beg;
    for (; i + 8 <= end; i += 8) {
        int2 e[8];
        #pragma unroll
        for (int j = 0; j < 8; ++j) e[j] = edges[i + j];
        half2v v[8];
        #pragma unroll
        for (int j = 0; j < 8; ++j)
            v[j] = *reinterpret_cast<const half2v*>(x + (size_t)e[j].x * DD + lane * 2);
        #pragma unroll
        for (int j = 0; j < 8; ++j) {
            float w = __int_as_float(e[j].y);
            a0 = fmaf((float)v[j].x, w, a0);
            a1 = fmaf((float)v[j].y, w, a1);
        }
    }
    for (; i < end; ++i) {
        int2 e0 = edges[i];
        half2v v0 = *reinterpret_cast<const half2v*>(x + (size_t)e0.x * DD + lane * 2);
        float w = __int_as_float(e0.y);
        a0 = fmaf((float)v0.x, w, a0);
        a1 = fmaf((float)v0.y, w, a1);
    }
    half2v o;
    o.x = (_Float16)a0; o.y = (_Float16)a1;
    *reinterpret_cast<half2v*>(out + (size_t)wid * DD + lane * 2) = o;
}

// ---------------- MFMA GEMM: out = relu(A @ W + b) [+ resid], LDS-free ----------
// A: [P x 128] fp16 row-major (P padded to 128). Wt: [128 x 128] fp16, Wt[n][k].
// 256 threads = 4 waves; wave w computes rows [blk*128 + w*32, +32).
__global__ __launch_bounds__(256) void k_gemm_mfma(const _Float16* __restrict__ A,
                                                   const _Float16* __restrict__ Wt,
                                                   const float* __restrict__ bias,
                                                   const _Float16* __restrict__ resid_h,
                                                   float* __restrict__ out_f32,
                                                   _Float16* __restrict__ out_f16,
                                                   int nrows) {
    int wave = threadIdx.x >> 6;
    int lane = threadIdx.x & 63;
    int row0 = blockIdx.x * 128 + wave * 32;
    int m = lane & 15;    // A row within 16-tile; also B column within 16-tile
    int q = lane >> 4;    // quad -> k offset q*8

    floatx4 acc[2][8];
    #pragma unroll
    for (int t = 0; t < 2; ++t)
        #pragma unroll
        for (int c = 0; c < 8; ++c)
            acc[t][c] = (floatx4){0.f, 0.f, 0.f, 0.f};

    #pragma unroll
    for (int ks = 0; ks < 4; ++ks) {
        int kbase = ks * 32 + q * 8;
        half8 a0 = *reinterpret_cast<const half8*>(A + (size_t)(row0 + m) * DD + kbase);
        half8 a1 = *reinterpret_cast<const half8*>(A + (size_t)(row0 + 16 + m) * DD + kbase);
        #pragma unroll
        for (int c = 0; c < 8; ++c) {
            half8 b = *reinterpret_cast<const half8*>(Wt + (size_t)(c * 16 + m) * DD + kbase);
            acc[0][c] = __builtin_amdgcn_mfma_f32_16x16x32_f16(a0, b, acc[0][c], 0, 0, 0);
            acc[1][c] = __builtin_amdgcn_mfma_f32_16x16x32_f16(a1, b, acc[1][c], 0, 0, 0);
        }
    }

    // C/D layout per 16x16 tile: col = lane&15, row = q*4 + reg
    #pragma unroll
    for (int t = 0; t < 2; ++t) {
        #pragma unroll
        for (int c = 0; c < 8; ++c) {
            int col = c * 16 + m;
            float bv = bias[col];
            #pragma unroll
            for (int r = 0; r < 4; ++r) {
                int row = row0 + t * 16 + q * 4 + r;
                if (row < nrows) {
                    float v = acc[t][c][r] + bv;
                    v = v > 0.f ? v : 0.f;
                    if (resid_h) v += (float)resid_h[(size_t)row * DD + col];
                    if (out_f32) out_f32[(size_t)row * DD + col] = v;
                    if (out_f16) out_f16[(size_t)row * DD + col] = (_Float16)v;
                }
            }
        }
    }
}

// ---------------- per-subgraph mean pool + target residual ----------------
__global__ __launch_bounds__(128) void k_pool(const float* __restrict__ h,
                                              const int* __restrict__ target,
                                              const float* __restrict__ size_subg,
                                              float* __restrict__ pooled, int SZ) {
    int b = blockIdx.x;
    int d = threadIdx.x;
    const float* hp = h + (size_t)b * SZ * DD;
    float s = 0.f;
    for (int n = 0; n < SZ; ++n) s += hp[(size_t)n * DD + d];
    int t = target[b];
    float p = s / size_subg[b] + h[(size_t)t * DD + d];
    pooled[b * DD + d] = p;
}

// ---------------- final: relu(pooled @ Wp + bp), L2-normalize rows ----------------
__global__ __launch_bounds__(128) void k_final(const float* __restrict__ pooled,
                                               const float* __restrict__ Wp,
                                               const float* __restrict__ bp,
                                               float* __restrict__ out) {
    __shared__ float p[DD];
    __shared__ float wsum[2];
    int b = blockIdx.x;
    int c = threadIdx.x;
    p[c] = pooled[b * DD + c];
    __syncthreads();
    float acc = 0.f;
    #pragma unroll 4
    for (int k = 0; k < DD; ++k) acc = fmaf(p[k], Wp[k * DD + c], acc);
    float e = acc + bp[c];
    e = e > 0.f ? e : 0.f;
    float sq = e * e;
    #pragma unroll
    for (int off = 32; off > 0; off >>= 1) sq += __shfl_down(sq, off, 64);
    int lane = c & 63, w = c >> 6;
    if (lane == 0) wsum[w] = sq;
    __syncthreads();
    float norm = sqrtf(wsum[0] + wsum[1]);
    float scale = 1.f / fmaxf(norm, 1e-12f);
    out[b * DD + c] = e * scale;
}

extern "C" void kernel_launch(void* const* d_in, const int* in_sizes, int n_in,
                              void* d_out, int out_size, void* d_ws, size_t ws_size,
                              hipStream_t stream) {
    const float* feat      = (const float*)d_in[0];
    const float* edge_w    = (const float*)d_in[1];
    const float* W1        = (const float*)d_in[2];
    const float* b1        = (const float*)d_in[3];
    const float* W2        = (const float*)d_in[4];
    const float* b2        = (const float*)d_in[5];
    const float* Wp        = (const float*)d_in[6];
    const float* bp        = (const float*)d_in[7];
    const float* size_subg = (const float*)d_in[8];
    const int*   edge_src  = (const int*)d_in[9];
    const int*   edge_dst  = (const int*)d_in[10];
    const int*   target    = (const int*)d_in[12];

    const int N  = in_sizes[0] / DD;
    const int E  = in_sizes[1];
    const int B  = in_sizes[8];
    const int SZ = N / B;

    const int gemmBlocks = (N + 127) / 128;
    const int P = gemmBlocks * 128;   // padded row count for MFMA A buffers

    char* ws = (char*)d_ws;
    size_t off = 0;
    auto alloc = [&](size_t bytes) {
        void* p = ws + off;
        off += (bytes + 255) & ~(size_t)255;
        return p;
    };
    // Region overlay: H (fp32, N*DD*4) reuses feat_h + agg1_h (both dead before gemm2).
    char* region0   = (char*)alloc((size_t)N * DD * 4 + 512);
    _Float16* feat_h = (_Float16*)region0;
    _Float16* agg1_h = (_Float16*)(region0 + (size_t)N * DD * 2);  // P*DD*2 <= N*DD*2 + 512? no:
    // P*DD*2 = (N padded) — P-N < 128 rows -> pad below covers it
    float*    H      = (float*)region0;
    _Float16* h1_h   = (_Float16*)alloc((size_t)P * DD * 2);
    _Float16* agg2_h = (_Float16*)alloc((size_t)P * DD * 2);
    _Float16* pad    = (_Float16*)alloc((size_t)(P - N + 2) * DD * 2);  // tail room for agg1_h
    (void)pad;
    _Float16* W1t    = (_Float16*)alloc((size_t)DD * DD * 2);
    _Float16* W2t    = (_Float16*)alloc((size_t)DD * DD * 2);
    int*   counts    = (int*)alloc((size_t)N * 4);
    int*   row_start = (int*)alloc(((size_t)N + 1) * 4);
    int*   cursor    = (int*)alloc((size_t)N * 4);
    int nb = (N + 1023) / 1024;
    int*   blockSums = (int*)alloc((size_t)nb * 4);
    int*   blockOffs = (int*)alloc((size_t)nb * 4);
    int2*  edges     = (int2*)alloc((size_t)E * 8);
    float* pooled    = (float*)alloc((size_t)B * DD * 4);

    // ---- CSR by dst ----
    hipMemsetAsync(counts, 0, (size_t)N * 4, stream);
    k_hist<<<(E + 255) / 256, 256, 0, stream>>>(edge_dst, counts, E);
    k_scan_block_sums<<<nb, 1024, 0, stream>>>(counts, blockSums, N);
    k_scan_offsets<<<1, 1024, 0, stream>>>(blockSums, blockOffs, nb, row_start + N);
    k_scan_final<<<nb, 1024, 0, stream>>>(counts, blockOffs, row_start, cursor, N);
    k_place<<<(E + 255) / 256, 256, 0, stream>>>(edge_src, edge_dst, edge_w, cursor,
                                                 edges, E);

    // ---- casts ----
    int n4 = N * DD / 4;
    k_cast_f2h<<<(n4 + 255) / 256, 256, 0, stream>>>(feat, feat_h, n4);
    k_cast_wT<<<64, 256, 0, stream>>>(W1, W1t);
    k_cast_wT<<<64, 256, 0, stream>>>(W2, W2t);

    int aggBlocks = (N * 64 + 255) / 256;   // one wave per node

    // layer 1: agg1 = A_hat @ feat ; h1 = relu(agg1 @ W1 + b1)  (fp16 out)
    k_aggregate_h<<<aggBlocks, 256, 0, stream>>>(feat_h, row_start, edges, agg1_h, N);
    k_gemm_mfma<<<gemmBlocks, 256, 0, stream>>>(agg1_h, W1t, b1, nullptr,
                                                nullptr, h1_h, N);
    // layer 2: agg2 = A_hat @ h1 ; h = h1 + relu(agg2 @ W2 + b2)  (fp32 out into H)
    k_aggregate_h<<<aggBlocks, 256, 0, stream>>>(h1_h, row_start, edges, agg2_h, N);
    k_gemm_mfma<<<gemmBlocks, 256, 0, stream>>>(agg2_h, W2t, b2, h1_h,
                                                H, nullptr, N);
    // pool + final
    k_pool<<<B, 128, 0, stream>>>(H, target, size_subg, pooled, SZ);
    k_final<<<B, 128, 0, stream>>>(pooled, Wp, bp, (float*)d_out);
}